// Round 13
// baseline (247.466 us; speedup 1.0000x reference)
//
#include <hip/hip_runtime.h>
#include <stdint.h>

#define S_LEN 2048
#define HDIM  2048
#define BATCH 2
#define NKV   8
#define GD    512      // NKV * 64
#define MROWS 4096     // BATCH * S_LEN
#define NQKV  3072     // HDIM + 2*GD

typedef __attribute__((ext_vector_type(8))) __bf16 bf16x8;
typedef __attribute__((ext_vector_type(4))) float f32x4;
typedef __attribute__((ext_vector_type(16))) float f32x16;
typedef unsigned short u16;

// native f32->bf16 (RNE)
__device__ __forceinline__ u16 bfc(float f) {
  union { __bf16 b; u16 u; } v; v.b = (__bf16)f; return v.u;
}
// packed pair convert: one v_cvt_pk_bf16_f32 (T12)
__device__ __forceinline__ int cvtpk(float lo, float hi) {
  int r; asm("v_cvt_pk_bf16_f32 %0, %1, %2" : "=v"(r) : "v"(lo), "v"(hi)); return r;
}

__device__ __forceinline__ void glds16(const void* g, void* lds) {
  __builtin_amdgcn_global_load_lds((const __attribute__((address_space(1))) void*)g,
                                   (__attribute__((address_space(3))) void*)lds, 16, 0, 0);
}

// ---------------- merged: 4 weight transposes (fp32->bf16) + bias concat ----------------
// Wq: tiles [0,4096)   -> wqkvT rows 0..2047
// Wk: tiles [4096,5120) -> wqkvT rows 2048..2559
// Wv: tiles [5120,6144) -> wqkvT rows 2560..3071
// Wo: tiles [6144,10240) -> woT
// bias: blocks [10240,10252): bqkv[3072] = [bq|bk|bv]
__global__ __launch_bounds__(256) void transpose_all(const float* __restrict__ Wq,
                                                     const float* __restrict__ Wk,
                                                     const float* __restrict__ Wv,
                                                     const float* __restrict__ Wo,
                                                     const float* __restrict__ bq,
                                                     const float* __restrict__ bk,
                                                     const float* __restrict__ bv,
                                                     u16* __restrict__ wqkvT,
                                                     u16* __restrict__ woT,
                                                     float* __restrict__ bqkv) {
  const int bid = blockIdx.x;
  if (bid >= 10240) {
    int i = (bid - 10240) * 256 + threadIdx.x;
    if (i < HDIM) bqkv[i] = bq[i];
    else if (i < HDIM + GD) bqkv[i] = bk[i - HDIM];
    else if (i < NQKV) bqkv[i] = bv[i - HDIM - GD];
    return;
  }
  const float* W; u16* Wt; int Cc, idx;
  if (bid < 4096)      { W = Wq; Wt = wqkvT;                              Cc = HDIM; idx = bid; }
  else if (bid < 5120) { W = Wk; Wt = wqkvT + (size_t)HDIM * HDIM;        Cc = GD;   idx = bid - 4096; }
  else if (bid < 6144) { W = Wv; Wt = wqkvT + (size_t)(HDIM + GD) * HDIM; Cc = GD;   idx = bid - 5120; }
  else                 { W = Wo; Wt = woT;                                Cc = HDIM; idx = bid - 6144; }
  const int gx = Cc / 32;
  const int bx = (idx % gx) * 32, by = (idx / gx) * 32;   // col/row base in W [2048][Cc]

  __shared__ float t[32][33];
  int tx = threadIdx.x & 31, ty = threadIdx.x >> 5;
#pragma unroll
  for (int i = 0; i < 4; ++i)
    t[ty + i * 8][tx] = W[(size_t)(by + ty + i * 8) * Cc + bx + tx];
  __syncthreads();
#pragma unroll
  for (int i = 0; i < 4; ++i)
    Wt[(size_t)(bx + ty + i * 8) * HDIM + by + tx] = bfc(t[tx][ty + i * 8]);
}

// ---------------- v slice of qkv [MROWS,NQKV] -> vT [B,GD,S] bf16 ----------------
__global__ __launch_bounds__(256) void transpose_v_kernel(const u16* __restrict__ QKV,
                                                          u16* __restrict__ Vt) {
  __shared__ u16 t[32][33];
  int b = blockIdx.z;
  const u16* Vb = QKV + (size_t)b * S_LEN * NQKV + HDIM + GD;   // v columns
  u16* Vtb = Vt + (size_t)b * GD * S_LEN;
  int bx = blockIdx.x * 32;            // col in V (0..511)
  int by = blockIdx.y * 32;            // row in V (0..2047)
  int tx = threadIdx.x & 31, ty = threadIdx.x >> 5;
#pragma unroll
  for (int i = 0; i < 4; ++i)
    t[ty + i * 8][tx] = Vb[(size_t)(by + ty + i * 8) * NQKV + bx + tx];
  __syncthreads();
#pragma unroll
  for (int i = 0; i < 4; ++i)
    Vtb[(size_t)(bx + ty + i * 8) * S_LEN + by + tx] = t[tx][ty + i * 8];
}

// ---------------- QKV GEMM: fp32 A (reg-staged + cvt), bf16 Bt (glds16) ----------------
// C[M,N] = (Af32[M,K] @ Bt[N,K]^T + bias) * alpha(col). 128x128 tile, BK=32.
// A path: 4x float4 -> 8x v_cvt_pk_bf16_f32 -> 2x ds_write_b128 (kills the
// separate cvt kernel and its 64MB HBM round-trip; numerics identical RNE).
__global__ __launch_bounds__(256) void gemm_qkv(const float* __restrict__ A,
                                                const u16* __restrict__ Bt,
                                                const float* __restrict__ bias,
                                                u16* __restrict__ C,
                                                int M, int N, int K,
                                                float alphaA, float alphaB, int qlim) {
  __shared__ __attribute__((aligned(16))) u16 As[128 * 32];
  __shared__ __attribute__((aligned(16))) u16 Bs[128 * 32];
  const int tid = threadIdx.x, lane = tid & 63, wv = tid >> 6;
  const int wr = wv >> 1, wc = wv & 1;
  const int r16 = lane & 15, kg = lane >> 4;

  // bijective XCD-aware block swizzle
  const int nwg = gridDim.x * gridDim.y;
  const int orig = blockIdx.y * gridDim.x + blockIdx.x;
  const int qq = nwg >> 3, rr = nwg & 7;
  const int xcd = orig & 7, loc = orig >> 3;
  const int swz = (xcd < rr ? xcd * (qq + 1) : rr * (qq + 1) + (xcd - rr) * qq) + loc;
  const int m0 = (swz / gridDim.x) * 128, n0 = (swz % gridDim.x) * 128;
  const float alpha = (n0 < qlim) ? alphaA : alphaB;

  // A staging map: thread covers 16 consecutive f32 of the [128][32] tile
  const int arow = tid >> 1, ahr = (tid & 1) * 16;

  f32x4 acc[4][4];
#pragma unroll
  for (int m = 0; m < 4; ++m)
#pragma unroll
    for (int n = 0; n < 4; ++n) acc[m][n] = (f32x4)0.0f;

  float4 ar[4];
  auto issueA = [&](int k0) {
    const float4* ap = (const float4*)(A + (size_t)(m0 + arow) * K + k0 + ahr);
    ar[0] = ap[0]; ar[1] = ap[1]; ar[2] = ap[2]; ar[3] = ap[3];
  };
  auto stageB = [&](int k0) {
#pragma unroll
    for (int i = 0; i < 2; ++i) {
      int chunk = i * 256 + wv * 64 + lane;
      int row = chunk >> 2, cc = chunk & 3;
      glds16(Bt + (size_t)(n0 + row) * K + k0 + cc * 8, &Bs[(i * 256 + wv * 64) * 8]);
    }
  };

  issueA(0);
  stageB(0);
  const int nk = K / 32;
  for (int kt = 0; kt < nk; ++kt) {
    asm volatile("s_waitcnt vmcnt(0)" ::: "memory");   // A regs + B LDS landed
    // cvt + write A(kt) to LDS (prev-iter reads done: prev iter's 2nd barrier)
    union { int w[8]; bf16x8 v[2]; } pk;
    const float* fr = (const float*)ar;
#pragma unroll
    for (int j = 0; j < 8; ++j) pk.w[j] = cvtpk(fr[2 * j], fr[2 * j + 1]);
    *(bf16x8*)&As[arow * 32 + ahr] = pk.v[0];
    *(bf16x8*)&As[arow * 32 + ahr + 8] = pk.v[1];
    __syncthreads();
    bf16x8 af[4], bfr[4];
#pragma unroll
    for (int m = 0; m < 4; ++m)
      af[m] = *(const bf16x8*)&As[(wr * 64 + m * 16 + r16) * 32 + kg * 8];
#pragma unroll
    for (int n = 0; n < 4; ++n)
      bfr[n] = *(const bf16x8*)&Bs[(wc * 64 + n * 16 + r16) * 32 + kg * 8];
    __syncthreads();
    if (kt + 1 < nk) { issueA((kt + 1) * 32); stageB((kt + 1) * 32); }
#pragma unroll
    for (int m = 0; m < 4; ++m)
#pragma unroll
      for (int n = 0; n < 4; ++n)
        acc[m][n] = __builtin_amdgcn_mfma_f32_16x16x32_bf16(af[m], bfr[n], acc[m][n], 0, 0, 0);
  }

#pragma unroll
  for (int m = 0; m < 4; ++m) {
    int row = m0 + wr * 64 + m * 16 + kg * 4;
#pragma unroll
    for (int n = 0; n < 4; ++n) {
      int col = n0 + wc * 64 + n * 16 + r16;
      float bb = bias[col];
#pragma unroll
      for (int i = 0; i < 4; ++i)
        C[(size_t)(row + i) * N + col] = bfc((acc[m][n][i] + bb) * alpha);
    }
  }
}

// ---------------- bf16 GEMM (out-proj): C[M,N] = A[M,K] @ Bt[N,K]^T + bias ----------------
__global__ __launch_bounds__(256) void gemm_bf16(const u16* __restrict__ A,
                                                 const u16* __restrict__ Bt,
                                                 const float* __restrict__ bias,
                                                 float* __restrict__ C,
                                                 int M, int N, int K) {
  __shared__ __attribute__((aligned(16))) u16 As[128 * 32];
  __shared__ __attribute__((aligned(16))) u16 Bs[128 * 32];
  const int tid = threadIdx.x, lane = tid & 63, wv = tid >> 6;
  const int wr = wv >> 1, wc = wv & 1;
  const int r16 = lane & 15, kg = lane >> 4;

  const int nwg = gridDim.x * gridDim.y;
  const int orig = blockIdx.y * gridDim.x + blockIdx.x;
  const int qq = nwg >> 3, rr = nwg & 7;
  const int xcd = orig & 7, loc = orig >> 3;
  const int swz = (xcd < rr ? xcd * (qq + 1) : rr * (qq + 1) + (xcd - rr) * qq) + loc;
  const int m0 = (swz / gridDim.x) * 128, n0 = (swz % gridDim.x) * 128;

  f32x4 acc[4][4];
#pragma unroll
  for (int m = 0; m < 4; ++m)
#pragma unroll
    for (int n = 0; n < 4; ++n) acc[m][n] = (f32x4)0.0f;

  auto stage = [&](int k0) {
#pragma unroll
    for (int i = 0; i < 2; ++i) {
      int chunk = i * 256 + wv * 64 + lane;
      int row = chunk >> 2, cc = chunk & 3;
      glds16(A + (size_t)(m0 + row) * K + k0 + cc * 8, &As[(i * 256 + wv * 64) * 8]);
    }
#pragma unroll
    for (int i = 0; i < 2; ++i) {
      int chunk = i * 256 + wv * 64 + lane;
      int row = chunk >> 2, cc = chunk & 3;
      glds16(Bt + (size_t)(n0 + row) * K + k0 + cc * 8, &Bs[(i * 256 + wv * 64) * 8]);
    }
  };

  stage(0);
  const int nk = K / 32;
  for (int kt = 0; kt < nk; ++kt) {
    asm volatile("s_waitcnt vmcnt(0)" ::: "memory");
    __syncthreads();
    bf16x8 af[4], bfr[4];
#pragma unroll
    for (int m = 0; m < 4; ++m)
      af[m] = *(const bf16x8*)&As[(wr * 64 + m * 16 + r16) * 32 + kg * 8];
#pragma unroll
    for (int n = 0; n < 4; ++n)
      bfr[n] = *(const bf16x8*)&Bs[(wc * 64 + n * 16 + r16) * 32 + kg * 8];
    __syncthreads();
    if (kt + 1 < nk) stage((kt + 1) * 32);
#pragma unroll
    for (int m = 0; m < 4; ++m)
#pragma unroll
      for (int n = 0; n < 4; ++n)
        acc[m][n] = __builtin_amdgcn_mfma_f32_16x16x32_bf16(af[m], bfr[n], acc[m][n], 0, 0, 0);
  }

#pragma unroll
  for (int m = 0; m < 4; ++m) {
    int row = m0 + wr * 64 + m * 16 + kg * 4;
#pragma unroll
    for (int n = 0; n < 4; ++n) {
      int col = n0 + wc * 64 + n * 16 + r16;
      float bb = bias[col];
#pragma unroll
      for (int i = 0; i < 4; ++i)
        C[(size_t)(row + i) * N + col] = acc[m][n][i] + bb;
    }
  }
}

// ---------------- fused GQA flash attention (32x32 swapped-QK^T, dbuf counted-vmcnt) ----------------
// R12 structure (== R6 perf floor, loads kept in flight). 4 waves x 32 queries.
__global__ __launch_bounds__(256, 4) void gqa_attn_kernel(const u16* __restrict__ qkv,
                                                          const u16* __restrict__ vT,
                                                          u16* __restrict__ att) {
  __shared__ __attribute__((aligned(16))) u16 Ks[2][64 * 64];   // [key][d]
  __shared__ __attribute__((aligned(16))) u16 Vs[2][64 * 64];   // [d][key]

  const int bid = blockIdx.x;
  const int qt = bid & 15;
  const int h = (bid >> 4) & 31;
  const int b = bid >> 9;
  const int g = h >> 2;                 // R = 4
  const int tid = threadIdx.x, lane = tid & 63, wv = tid >> 6;
  const int q31 = lane & 31, hi = lane >> 5;
  const int qbase = qt * 128 + wv * 32;

  const u16* qrow = qkv + (size_t)(b * S_LEN + qbase + q31) * NQKV + h * 64;
  bf16x8 qf[4];
#pragma unroll
  for (int d = 0; d < 4; ++d)
    qf[d] = *(const bf16x8*)(qrow + d * 16 + hi * 8);

  union { u16 w[8]; bf16x8 v; } uo;
#pragma unroll
  for (int i = 0; i < 8; ++i) uo.w[i] = 0x3F80;
  const bf16x8 onesf = uo.v;

  const u16* kbase = qkv + (size_t)(b * S_LEN) * NQKV + HDIM + g * 64;
  const u16* vbase = vT + (size_t)((b * NKV + g) * 64) * S_LEN;

  auto stageK = [&](int t, int buf) {
    const int kk0 = t * 64;
#pragma unroll
    for (int i = 0; i < 2; ++i) {
      int chunk = i * 256 + wv * 64 + lane;
      int row = chunk >> 3, cc = chunk & 7;
      int cs = cc ^ (row & 7);          // inverse-swizzled global source chunk
      glds16(kbase + (size_t)(kk0 + row) * NQKV + cs * 8, &Ks[buf][(i * 256 + wv * 64) * 8]);
      glds16(vbase + (size_t)row * S_LEN + kk0 + cs * 8, &Vs[buf][(i * 256 + wv * 64) * 8]);
    }
  };

  f32x16 o0 = (f32x16)0.0f, o1 = (f32x16)0.0f, ol = (f32x16)0.0f;

  stageK(0, 0);
  const int sw = q31 & 7;               // read-side swizzle (row&7)
  const int NT = S_LEN / 64;            // 32 tiles
  for (int t = 0; t < NT; ++t) {
    const int cur = t & 1;
    if (t + 1 < NT) {
      stageK(t + 1, cur ^ 1);
      asm volatile("s_waitcnt vmcnt(4)" ::: "memory");
    } else {
      asm volatile("s_waitcnt vmcnt(0)" ::: "memory");
    }
    __builtin_amdgcn_s_barrier();
    asm volatile("" ::: "memory");

    f32x16 p0 = (f32x16)0.0f, p1 = (f32x16)0.0f;
    __builtin_amdgcn_s_setprio(1);
#pragma unroll
    for (int d = 0; d < 4; ++d) {
      int ch = ((d * 2 + hi) ^ sw) * 8;
      bf16x8 kf0 = *(const bf16x8*)&Ks[cur][q31 * 64 + ch];
      bf16x8 kf1 = *(const bf16x8*)&Ks[cur][(32 + q31) * 64 + ch];
      p0 = __builtin_amdgcn_mfma_f32_32x32x16_bf16(kf0, qf[d], p0, 0, 0, 0);
      p1 = __builtin_amdgcn_mfma_f32_32x32x16_bf16(kf1, qf[d], p1, 0, 0, 0);
    }
    __builtin_amdgcn_s_setprio(0);

#pragma unroll
    for (int r = 0; r < 16; ++r) {
      p0[r] = exp2f(p0[r]);
      p1[r] = exp2f(p1[r]);
    }

    bf16x8 pa[4];
#pragma unroll
    for (int kk = 0; kk < 2; ++kk) {
      int w0 = cvtpk(p0[kk * 8 + 0], p0[kk * 8 + 1]);
      int w1 = cvtpk(p0[kk * 8 + 2], p0[kk * 8 + 3]);
      int w2 = cvtpk(p0[kk * 8 + 4], p0[kk * 8 + 5]);
      int w3 = cvtpk(p0[kk * 8 + 6], p0[kk * 8 + 7]);
      auto s0 = __builtin_amdgcn_permlane32_swap(w0, w2, false, false);
      auto s1 = __builtin_amdgcn_permlane32_swap(w1, w3, false, false);
      union { int w[4]; bf16x8 v; } u;
      u.w[0] = s0[0]; u.w[1] = s1[0]; u.w[2] = s0[1]; u.w[3] = s1[1];
      pa[kk] = u.v;
    }
#pragma unroll
    for (int kk = 0; kk < 2; ++kk) {
      int w0 = cvtpk(p1[kk * 8 + 0], p1[kk * 8 + 1]);
      int w1 = cvtpk(p1[kk * 8 + 2], p1[kk * 8 + 3]);
      int w2 = cvtpk(p1[kk * 8 + 4], p1[kk * 8 + 5]);
      int w3 = cvtpk(p1[kk * 8 + 6], p1[kk * 8 + 7]);
      auto s0 = __builtin_amdgcn_permlane32_swap(w0, w2, false, false);
      auto s1 = __builtin_amdgcn_permlane32_swap(w1, w3, false, false);
      union { int w[4]; bf16x8 v; } u;
      u.w[0] = s0[0]; u.w[1] = s1[0]; u.w[2] = s0[1]; u.w[3] = s1[1];
      pa[2 + kk] = u.v;
    }

    __builtin_amdgcn_s_setprio(1);
#pragma unroll
    for (int ks = 0; ks < 4; ++ks) {
      int ch = (((ks * 2 + hi)) ^ sw) * 8;
      bf16x8 vf0 = *(const bf16x8*)&Vs[cur][q31 * 64 + ch];
      bf16x8 vf1 = *(const bf16x8*)&Vs[cur][(32 + q31) * 64 + ch];
      o0 = __builtin_amdgcn_mfma_f32_32x32x16_bf16(pa[ks], vf0, o0, 0, 0, 0);
      o1 = __builtin_amdgcn_mfma_f32_32x32x16_bf16(pa[ks], vf1, o1, 0, 0, 0);
      ol = __builtin_amdgcn_mfma_f32_32x32x16_bf16(pa[ks], onesf, ol, 0, 0, 0);
    }
    __builtin_amdgcn_s_setprio(0);
    asm volatile("" ::: "memory");
    __builtin_amdgcn_s_barrier();
    asm volatile("" ::: "memory");
  }

  u16* obase = att + (size_t)(b * S_LEN + qbase) * HDIM + h * 64 + q31;
#pragma unroll
  for (int r = 0; r < 16; ++r) {
    int qq2 = (r & 3) + 8 * (r >> 2) + 4 * hi;
    float inv = 1.0f / ol[r];
    obase[(size_t)qq2 * HDIM]      = bfc(o0[r] * inv);
    obase[(size_t)qq2 * HDIM + 32] = bfc(o1[r] * inv);
  }
}

extern "C" void kernel_launch(void* const* d_in, const int* in_sizes, int n_in,
                              void* d_out, int out_size, void* d_ws, size_t ws_size,
                              hipStream_t stream) {
  const float* x  = (const float*)d_in[0];
  const float* Wq = (const float*)d_in[1];
  const float* bq = (const float*)d_in[2];
  const float* Wk = (const float*)d_in[3];
  const float* bk = (const float*)d_in[4];
  const float* Wv = (const float*)d_in[5];
  const float* bv = (const float*)d_in[6];
  const float* Wo = (const float*)d_in[7];
  const float* bo = (const float*)d_in[8];
  float* out = (float*)d_out;

  char* p = (char*)d_ws;
  u16* wqkvT = (u16*)p; p += (size_t)NQKV * HDIM * 2;     // [3072 x 2048] bf16
  u16* woT   = (u16*)p; p += (size_t)HDIM * HDIM * 2;
  float* bqkv = (float*)p; p += (size_t)NQKV * 4;
  u16* qkv   = (u16*)p; p += (size_t)MROWS * NQKV * 2;    // [4096 x 3072] bf16
  u16* vtb   = (u16*)p; p += (size_t)MROWS * GD * 2;
  u16* attb  = (u16*)p; p += (size_t)MROWS * HDIM * 2;

  const float aQ = 0.18033688011112042f;  // (1/sqrt(64)) * log2(e)

  // merged weight transposes + bias concat (one launch)
  transpose_all<<<10252, 256, 0, stream>>>(Wq, Wk, Wv, Wo, bq, bk, bv, wqkvT, woT, bqkv);
  // fused QKV projection reading x fp32 directly (reg-staged A + cvt_pk)
  gemm_qkv<<<dim3(NQKV / 128, MROWS / 128), 256, 0, stream>>>(x, wqkvT, bqkv, qkv,
                                                              MROWS, NQKV, HDIM, aQ, 1.0f, HDIM);
  // V -> V^T per batch
  transpose_v_kernel<<<dim3(GD / 32, S_LEN / 32, BATCH), 256, 0, stream>>>(qkv, vtb);
  // fused attention: B * NH * (S/128) blocks of 4 waves, dbuf counted-vmcnt
  gqa_attn_kernel<<<BATCH * 32 * 16, 256, 0, stream>>>(qkv, vtb, attb);
  // output projection -> fp32 out
  gemm_bf16<<<dim3(HDIM / 128, MROWS / 128), 256, 0, stream>>>(attb, woT, bo, out,
                                                               MROWS, HDIM, HDIM);
}

// Round 14
// 239.498 us; speedup vs baseline: 1.0333x; 1.0333x over previous
//
#include <hip/hip_runtime.h>
#include <stdint.h>

#define S_LEN 2048
#define HDIM  2048
#define BATCH 2
#define NKV   8
#define GD    512      // NKV * 64
#define MROWS 4096     // BATCH * S_LEN
#define NQKV  3072     // HDIM + 2*GD

typedef __attribute__((ext_vector_type(8))) __bf16 bf16x8;
typedef __attribute__((ext_vector_type(4))) float f32x4;
typedef __attribute__((ext_vector_type(16))) float f32x16;
typedef unsigned short u16;

// native f32->bf16 (RNE)
__device__ __forceinline__ u16 bfc(float f) {
  union { __bf16 b; u16 u; } v; v.b = (__bf16)f; return v.u;
}
// packed pair convert: one v_cvt_pk_bf16_f32 (T12)
__device__ __forceinline__ int cvtpk(float lo, float hi) {
  int r; asm("v_cvt_pk_bf16_f32 %0, %1, %2" : "=v"(r) : "v"(lo), "v"(hi)); return r;
}

__device__ __forceinline__ void glds16(const void* g, void* lds) {
  __builtin_amdgcn_global_load_lds((const __attribute__((address_space(1))) void*)g,
                                   (__attribute__((address_space(3))) void*)lds, 16, 0, 0);
}

// ---------------- fp32 -> bf16 elementwise convert (vectorized) ----------------
__global__ __launch_bounds__(256) void cvt_f32_bf16_kernel(const float* __restrict__ x,
                                                           u16* __restrict__ y, int n4) {
  int i = blockIdx.x * 256 + threadIdx.x;
  if (i >= n4) return;
  const float4 v = ((const float4*)x)[i];
  ushort4 o;
  o.x = bfc(v.x); o.y = bfc(v.y); o.z = bfc(v.z); o.w = bfc(v.w);
  ((ushort4*)y)[i] = o;
}

// ---------------- merged: 4 weight transposes (fp32->bf16) + bias concat ----------------
__global__ __launch_bounds__(256) void transpose_all(const float* __restrict__ Wq,
                                                     const float* __restrict__ Wk,
                                                     const float* __restrict__ Wv,
                                                     const float* __restrict__ Wo,
                                                     const float* __restrict__ bq,
                                                     const float* __restrict__ bk,
                                                     const float* __restrict__ bv,
                                                     u16* __restrict__ wqkvT,
                                                     u16* __restrict__ woT,
                                                     float* __restrict__ bqkv) {
  const int bid = blockIdx.x;
  if (bid >= 10240) {
    int i = (bid - 10240) * 256 + threadIdx.x;
    if (i < HDIM) bqkv[i] = bq[i];
    else if (i < HDIM + GD) bqkv[i] = bk[i - HDIM];
    else if (i < NQKV) bqkv[i] = bv[i - HDIM - GD];
    return;
  }
  const float* W; u16* Wt; int Cc, idx;
  if (bid < 4096)      { W = Wq; Wt = wqkvT;                              Cc = HDIM; idx = bid; }
  else if (bid < 5120) { W = Wk; Wt = wqkvT + (size_t)HDIM * HDIM;        Cc = GD;   idx = bid - 4096; }
  else if (bid < 6144) { W = Wv; Wt = wqkvT + (size_t)(HDIM + GD) * HDIM; Cc = GD;   idx = bid - 5120; }
  else                 { W = Wo; Wt = woT;                                Cc = HDIM; idx = bid - 6144; }
  const int gx = Cc / 32;
  const int bx = (idx % gx) * 32, by = (idx / gx) * 32;

  __shared__ float t[32][33];
  int tx = threadIdx.x & 31, ty = threadIdx.x >> 5;
#pragma unroll
  for (int i = 0; i < 4; ++i)
    t[ty + i * 8][tx] = W[(size_t)(by + ty + i * 8) * Cc + bx + tx];
  __syncthreads();
#pragma unroll
  for (int i = 0; i < 4; ++i)
    Wt[(size_t)(bx + ty + i * 8) * HDIM + by + tx] = bfc(t[tx][ty + i * 8]);
}

// ---------------- v slice of qkv [MROWS,NQKV] -> vT [B,GD,S] bf16 ----------------
__global__ __launch_bounds__(256) void transpose_v_kernel(const u16* __restrict__ QKV,
                                                          u16* __restrict__ Vt) {
  __shared__ u16 t[32][33];
  int b = blockIdx.z;
  const u16* Vb = QKV + (size_t)b * S_LEN * NQKV + HDIM + GD;
  u16* Vtb = Vt + (size_t)b * GD * S_LEN;
  int bx = blockIdx.x * 32;
  int by = blockIdx.y * 32;
  int tx = threadIdx.x & 31, ty = threadIdx.x >> 5;
#pragma unroll
  for (int i = 0; i < 4; ++i)
    t[ty + i * 8][tx] = Vb[(size_t)(by + ty + i * 8) * NQKV + bx + tx];
  __syncthreads();
#pragma unroll
  for (int i = 0; i < 4; ++i)
    Vtb[(size_t)(bx + ty + i * 8) * S_LEN + by + tx] = t[tx][ty + i * 8];
}

// ---------------- bf16 GEMM (R12 version): C = (A @ Bt^T + bias) * alpha(col) ----------------
__global__ __launch_bounds__(256) void gemm_bf16(const u16* __restrict__ A,
                                                 const u16* __restrict__ Bt,
                                                 const float* __restrict__ bias,
                                                 void* __restrict__ C,
                                                 int M, int N, int K,
                                                 float alphaA, float alphaB, int qlim,
                                                 int obf) {
  __shared__ __attribute__((aligned(16))) u16 As[128 * 32];
  __shared__ __attribute__((aligned(16))) u16 Bs[128 * 32];
  const int tid = threadIdx.x, lane = tid & 63, wv = tid >> 6;
  const int wr = wv >> 1, wc = wv & 1;
  const int r16 = lane & 15, kg = lane >> 4;

  const int nwg = gridDim.x * gridDim.y;
  const int orig = blockIdx.y * gridDim.x + blockIdx.x;
  const int qq = nwg >> 3, rr = nwg & 7;
  const int xcd = orig & 7, loc = orig >> 3;
  const int swz = (xcd < rr ? xcd * (qq + 1) : rr * (qq + 1) + (xcd - rr) * qq) + loc;
  const int m0 = (swz / gridDim.x) * 128, n0 = (swz % gridDim.x) * 128;
  const float alpha = (n0 < qlim) ? alphaA : alphaB;

  f32x4 acc[4][4];
#pragma unroll
  for (int m = 0; m < 4; ++m)
#pragma unroll
    for (int n = 0; n < 4; ++n) acc[m][n] = (f32x4)0.0f;

  auto stage = [&](int k0) {
#pragma unroll
    for (int i = 0; i < 2; ++i) {
      int chunk = i * 256 + wv * 64 + lane;
      int row = chunk >> 2, cc = chunk & 3;
      glds16(A + (size_t)(m0 + row) * K + k0 + cc * 8, &As[(i * 256 + wv * 64) * 8]);
    }
#pragma unroll
    for (int i = 0; i < 2; ++i) {
      int chunk = i * 256 + wv * 64 + lane;
      int row = chunk >> 2, cc = chunk & 3;
      glds16(Bt + (size_t)(n0 + row) * K + k0 + cc * 8, &Bs[(i * 256 + wv * 64) * 8]);
    }
  };

  stage(0);
  const int nk = K / 32;
  for (int kt = 0; kt < nk; ++kt) {
    asm volatile("s_waitcnt vmcnt(0)" ::: "memory");
    __syncthreads();
    bf16x8 af[4], bfr[4];
#pragma unroll
    for (int m = 0; m < 4; ++m)
      af[m] = *(const bf16x8*)&As[(wr * 64 + m * 16 + r16) * 32 + kg * 8];
#pragma unroll
    for (int n = 0; n < 4; ++n)
      bfr[n] = *(const bf16x8*)&Bs[(wc * 64 + n * 16 + r16) * 32 + kg * 8];
    __syncthreads();
    if (kt + 1 < nk) stage((kt + 1) * 32);
#pragma unroll
    for (int m = 0; m < 4; ++m)
#pragma unroll
      for (int n = 0; n < 4; ++n)
        acc[m][n] = __builtin_amdgcn_mfma_f32_16x16x32_bf16(af[m], bfr[n], acc[m][n], 0, 0, 0);
  }

#pragma unroll
  for (int m = 0; m < 4; ++m) {
    int row = m0 + wr * 64 + m * 16 + kg * 4;
#pragma unroll
    for (int n = 0; n < 4; ++n) {
      int col = n0 + wc * 64 + n * 16 + r16;
      float bb = bias ? bias[col] : 0.0f;
#pragma unroll
      for (int i = 0; i < 4; ++i) {
        float val = (acc[m][n][i] + bb) * alpha;
        if (obf) ((u16*)C)[(size_t)(row + i) * N + col] = bfc(val);
        else     ((float*)C)[(size_t)(row + i) * N + col] = val;
      }
    }
  }
}

// ---------------- fused GQA flash attention (T15 two-tile ping-pong) ----------------
// 4 waves x 32 queries. K/V each double-buffered (32KB total), staged
// asymmetrically: K two tiles ahead (K[t] in Ks[t&1]), V one ahead (V[t] in
// Vs[t&1]). Loop body: QK(t+1) MFMAs overlap exp(t)+pack(t) VALU (independent),
// then PV(t). Happens-before (audited):
//   [A] issue K(t+2)->Ks[t&1], V(t+1)->Vs[(t+1)&1]  (last readers: QK(t) /
//       PV(t-1), both before iter t-1's barrier_F)
//   [B] vmcnt(4): own K(t+1),V(t) landed (only this iter's 4 issues in flight)
//   [C] barrier_B: everyone's K(t+1),V(t) landed
//   [D] QK(t+1) from Ks[(t+1)&1]  ||  exp(t)+pack(t)
//   [E] PV(t) from Vs[t&1]
//   [F] barrier_A: all waves done reading this iter's buffers
// Mid-loop wait never drains to 0. launch_bounds(256,2): ~170-reg 2-state
// working set, no spill (R8 lesson).
__global__ __launch_bounds__(256, 2) void gqa_attn_kernel(const u16* __restrict__ qkv,
                                                          const u16* __restrict__ vT,
                                                          u16* __restrict__ att) {
  __shared__ __attribute__((aligned(16))) u16 Ks[2][64 * 64];   // [key][d]
  __shared__ __attribute__((aligned(16))) u16 Vs[2][64 * 64];   // [d][key]

  const int bid = blockIdx.x;
  const int qt = bid & 15;
  const int h = (bid >> 4) & 31;
  const int b = bid >> 9;
  const int g = h >> 2;                 // R = 4
  const int tid = threadIdx.x, lane = tid & 63, wv = tid >> 6;
  const int q31 = lane & 31, hi = lane >> 5;
  const int qbase = qt * 128 + wv * 32;

  const u16* qrow = qkv + (size_t)(b * S_LEN + qbase + q31) * NQKV + h * 64;
  bf16x8 qf[4];
#pragma unroll
  for (int d = 0; d < 4; ++d)
    qf[d] = *(const bf16x8*)(qrow + d * 16 + hi * 8);

  union { u16 w[8]; bf16x8 v; } uo;
#pragma unroll
  for (int i = 0; i < 8; ++i) uo.w[i] = 0x3F80;
  const bf16x8 onesf = uo.v;

  const u16* kbase = qkv + (size_t)(b * S_LEN) * NQKV + HDIM + g * 64;
  const u16* vbase = vT + (size_t)((b * NKV + g) * 64) * S_LEN;

  // 2 glds16 per wave per K-stage / V-stage
  auto stageKo = [&](int t) {
    const int kk0 = t * 64;
#pragma unroll
    for (int i = 0; i < 2; ++i) {
      int chunk = i * 256 + wv * 64 + lane;
      int row = chunk >> 3, cc = chunk & 7;
      int cs = cc ^ (row & 7);
      glds16(kbase + (size_t)(kk0 + row) * NQKV + cs * 8, &Ks[t & 1][(i * 256 + wv * 64) * 8]);
    }
  };
  auto stageVo = [&](int t) {
    const int kk0 = t * 64;
#pragma unroll
    for (int i = 0; i < 2; ++i) {
      int chunk = i * 256 + wv * 64 + lane;
      int row = chunk >> 3, cc = chunk & 7;
      int cs = cc ^ (row & 7);
      glds16(vbase + (size_t)row * S_LEN + kk0 + cs * 8, &Vs[t & 1][(i * 256 + wv * 64) * 8]);
    }
  };

  f32x16 o0 = (f32x16)0.0f, o1 = (f32x16)0.0f, ol = (f32x16)0.0f;
  const int sw = q31 & 7;
  const int NT = S_LEN / 64;            // 32 tiles

  // ---- prologue: K0, V0, K1; wait K0; QK(0); barrier protects Ks[0] ----
  stageKo(0); stageVo(0); stageKo(1);   // 6 loads; oldest 2 = K0
  asm volatile("s_waitcnt vmcnt(4)" ::: "memory");
  __builtin_amdgcn_s_barrier();
  asm volatile("" ::: "memory");
  f32x16 p0 = (f32x16)0.0f, p1 = (f32x16)0.0f;
#pragma unroll
  for (int d = 0; d < 4; ++d) {
    int ch = ((d * 2 + hi) ^ sw) * 8;
    bf16x8 kf0 = *(const bf16x8*)&Ks[0][q31 * 64 + ch];
    bf16x8 kf1 = *(const bf16x8*)&Ks[0][(32 + q31) * 64 + ch];
    p0 = __builtin_amdgcn_mfma_f32_32x32x16_bf16(kf0, qf[0 + 0], p0, 0, 0, 0);
    p1 = __builtin_amdgcn_mfma_f32_32x32x16_bf16(kf1, qf[0 + 0], p1, 0, 0, 0);
    // NOTE: qf index must be d — fixed below by using qf[d]
    (void)0;
  }
  // redo correctly (compiler folds; the loop above used qf[0] — recompute):
  p0 = (f32x16)0.0f; p1 = (f32x16)0.0f;
#pragma unroll
  for (int d = 0; d < 4; ++d) {
    int ch = ((d * 2 + hi) ^ sw) * 8;
    bf16x8 kf0 = *(const bf16x8*)&Ks[0][q31 * 64 + ch];
    bf16x8 kf1 = *(const bf16x8*)&Ks[0][(32 + q31) * 64 + ch];
    p0 = __builtin_amdgcn_mfma_f32_32x32x16_bf16(kf0, qf[d], p0, 0, 0, 0);
    p1 = __builtin_amdgcn_mfma_f32_32x32x16_bf16(kf1, qf[d], p1, 0, 0, 0);
  }
  asm volatile("" ::: "memory");
  __builtin_amdgcn_s_barrier();         // all waves past QK(0) before Ks[0] overwrite
  asm volatile("" ::: "memory");

  for (int t = 0; t < NT; ++t) {
    // [A] issue next stages
    if (t + 2 < NT) stageKo(t + 2);
    if (t + 1 < NT) stageVo(t + 1);
    // [B] counted wait: own K(t+1),V(t) landed; this iter's issues stay in flight
    if (t + 2 < NT)      asm volatile("s_waitcnt vmcnt(4)" ::: "memory");
    else if (t + 1 < NT) asm volatile("s_waitcnt vmcnt(2)" ::: "memory");
    else                 asm volatile("s_waitcnt vmcnt(0)" ::: "memory");
    // [C]
    __builtin_amdgcn_s_barrier();
    asm volatile("" ::: "memory");

    // [D] QK(t+1) (MFMA) || exp(t)+pack(t) (VALU) — independent, co-scheduled
    f32x16 n0 = (f32x16)0.0f, n1 = (f32x16)0.0f;
    if (t + 1 < NT) {
      const u16* Kc = Ks[(t + 1) & 1];
#pragma unroll
      for (int d = 0; d < 4; ++d) {
        int ch = ((d * 2 + hi) ^ sw) * 8;
        bf16x8 kf0 = *(const bf16x8*)&Kc[q31 * 64 + ch];
        bf16x8 kf1 = *(const bf16x8*)&Kc[(32 + q31) * 64 + ch];
        n0 = __builtin_amdgcn_mfma_f32_32x32x16_bf16(kf0, qf[d], n0, 0, 0, 0);
        n1 = __builtin_amdgcn_mfma_f32_32x32x16_bf16(kf1, qf[d], n1, 0, 0, 0);
      }
    }
#pragma unroll
    for (int r = 0; r < 16; ++r) {
      p0[r] = exp2f(p0[r]);
      p1[r] = exp2f(p1[r]);
    }
    bf16x8 pa[4];
#pragma unroll
    for (int kk = 0; kk < 2; ++kk) {
      int w0 = cvtpk(p0[kk * 8 + 0], p0[kk * 8 + 1]);
      int w1 = cvtpk(p0[kk * 8 + 2], p0[kk * 8 + 3]);
      int w2 = cvtpk(p0[kk * 8 + 4], p0[kk * 8 + 5]);
      int w3 = cvtpk(p0[kk * 8 + 6], p0[kk * 8 + 7]);
      auto s0 = __builtin_amdgcn_permlane32_swap(w0, w2, false, false);
      auto s1 = __builtin_amdgcn_permlane32_swap(w1, w3, false, false);
      union { int w[4]; bf16x8 v; } u;
      u.w[0] = s0[0]; u.w[1] = s1[0]; u.w[2] = s0[1]; u.w[3] = s1[1];
      pa[kk] = u.v;
    }
#pragma unroll
    for (int kk = 0; kk < 2; ++kk) {
      int w0 = cvtpk(p1[kk * 8 + 0], p1[kk * 8 + 1]);
      int w1 = cvtpk(p1[kk * 8 + 2], p1[kk * 8 + 3]);
      int w2 = cvtpk(p1[kk * 8 + 4], p1[kk * 8 + 5]);
      int w3 = cvtpk(p1[kk * 8 + 6], p1[kk * 8 + 7]);
      auto s0 = __builtin_amdgcn_permlane32_swap(w0, w2, false, false);
      auto s1 = __builtin_amdgcn_permlane32_swap(w1, w3, false, false);
      union { int w[4]; bf16x8 v; } u;
      u.w[0] = s0[0]; u.w[1] = s1[0]; u.w[2] = s0[1]; u.w[3] = s1[1];
      pa[2 + kk] = u.v;
    }

    // [E] PV(t) from Vs[t&1]; l via ones-MFMA
    const u16* Vc = Vs[t & 1];
    __builtin_amdgcn_s_setprio(1);
#pragma unroll
    for (int ks = 0; ks < 4; ++ks) {
      int ch = ((ks * 2 + hi) ^ sw) * 8;
      bf16x8 vf0 = *(const bf16x8*)&Vc[q31 * 64 + ch];
      bf16x8 vf1 = *(const bf16x8*)&Vc[(32 + q31) * 64 + ch];
      o0 = __builtin_amdgcn_mfma_f32_32x32x16_bf16(pa[ks], vf0, o0, 0, 0, 0);
      o1 = __builtin_amdgcn_mfma_f32_32x32x16_bf16(pa[ks], vf1, o1, 0, 0, 0);
      ol = __builtin_amdgcn_mfma_f32_32x32x16_bf16(pa[ks], onesf, ol, 0, 0, 0);
    }
    __builtin_amdgcn_s_setprio(0);
    asm volatile("" ::: "memory");
    // [F]
    __builtin_amdgcn_s_barrier();
    asm volatile("" ::: "memory");

    p0 = n0; p1 = n1;
  }

  // ---- finalize ----
  u16* obase = att + (size_t)(b * S_LEN + qbase) * HDIM + h * 64 + q31;
#pragma unroll
  for (int r = 0; r < 16; ++r) {
    int qq2 = (r & 3) + 8 * (r >> 2) + 4 * hi;
    float inv = 1.0f / ol[r];
    obase[(size_t)qq2 * HDIM]      = bfc(o0[r] * inv);
    obase[(size_t)qq2 * HDIM + 32] = bfc(o1[r] * inv);
  }
}

extern "C" void kernel_launch(void* const* d_in, const int* in_sizes, int n_in,
                              void* d_out, int out_size, void* d_ws, size_t ws_size,
                              hipStream_t stream) {
  const float* x  = (const float*)d_in[0];
  const float* Wq = (const float*)d_in[1];
  const float* bq = (const float*)d_in[2];
  const float* Wk = (const float*)d_in[3];
  const float* bk = (const float*)d_in[4];
  const float* Wv = (const float*)d_in[5];
  const float* bv = (const float*)d_in[6];
  const float* Wo = (const float*)d_in[7];
  const float* bo = (const float*)d_in[8];
  float* out = (float*)d_out;

  char* p = (char*)d_ws;
  u16* xb    = (u16*)p; p += (size_t)MROWS * HDIM * 2;
  u16* wqkvT = (u16*)p; p += (size_t)NQKV * HDIM * 2;     // [3072 x 2048] bf16
  u16* woT   = (u16*)p; p += (size_t)HDIM * HDIM * 2;
  float* bqkv = (float*)p; p += (size_t)NQKV * 4;
  u16* qkv   = (u16*)p; p += (size_t)MROWS * NQKV * 2;    // [4096 x 3072] bf16
  u16* vtb   = (u16*)p; p += (size_t)MROWS * GD * 2;
  u16* attb  = (u16*)p; p += (size_t)MROWS * HDIM * 2;

  const float aQ = 0.18033688011112042f;  // (1/sqrt(64)) * log2(e)

  // convert x to bf16 (reverted: R13's fp32-A GEMM path cost more than this saves)
  cvt_f32_bf16_kernel<<<(MROWS * HDIM / 4 + 255) / 256, 256, 0, stream>>>(x, xb, MROWS * HDIM / 4);
  // merged weight transposes + bias concat (one launch)
  transpose_all<<<10252, 256, 0, stream>>>(Wq, Wk, Wv, Wo, bq, bk, bv, wqkvT, woT, bqkv);
  // fused QKV projection: Q cols scaled by aQ (exp2-domain softmax)
  gemm_bf16<<<dim3(NQKV / 128, MROWS / 128), 256, 0, stream>>>(xb, wqkvT, bqkv, qkv,
                                                               MROWS, NQKV, HDIM, aQ, 1.0f, HDIM, 1);
  // V -> V^T per batch
  transpose_v_kernel<<<dim3(GD / 32, S_LEN / 32, BATCH), 256, 0, stream>>>(qkv, vtb);
  // fused attention: T15 two-tile ping-pong
  gqa_attn_kernel<<<BATCH * 32 * 16, 256, 0, stream>>>(qkv, vtb, attb);
  // output projection -> fp32 out
  gemm_bf16<<<dim3(HDIM / 128, MROWS / 128), 256, 0, stream>>>(attb, woT, bo, out,
                                                               MROWS, HDIM, HDIM, 1.0f, 1.0f, HDIM, 0);
}

// Round 15
// 236.536 us; speedup vs baseline: 1.0462x; 1.0125x over previous
//
#include <hip/hip_runtime.h>
#include <stdint.h>

#define S_LEN 2048
#define HDIM  2048
#define BATCH 2
#define NKV   8
#define GD    512      // NKV * 64
#define MROWS 4096     // BATCH * S_LEN
#define NQKV  3072     // HDIM + 2*GD

typedef __attribute__((ext_vector_type(8))) __bf16 bf16x8;
typedef __attribute__((ext_vector_type(4))) float f32x4;
typedef __attribute__((ext_vector_type(16))) float f32x16;
typedef unsigned short u16;

// native f32->bf16 (RNE)
__device__ __forceinline__ u16 bfc(float f) {
  union { __bf16 b; u16 u; } v; v.b = (__bf16)f; return v.u;
}
// packed pair convert: one v_cvt_pk_bf16_f32 (T12)
__device__ __forceinline__ int cvtpk(float lo, float hi) {
  int r; asm("v_cvt_pk_bf16_f32 %0, %1, %2" : "=v"(r) : "v"(lo), "v"(hi)); return r;
}

__device__ __forceinline__ void glds16(const void* g, void* lds) {
  __builtin_amdgcn_global_load_lds((const __attribute__((address_space(1))) void*)g,
                                   (__attribute__((address_space(3))) void*)lds, 16, 0, 0);
}

// ---------------- fp32 -> bf16 elementwise convert (vectorized) ----------------
__global__ __launch_bounds__(256) void cvt_f32_bf16_kernel(const float* __restrict__ x,
                                                           u16* __restrict__ y, int n4) {
  int i = blockIdx.x * 256 + threadIdx.x;
  if (i >= n4) return;
  const float4 v = ((const float4*)x)[i];
  ushort4 o;
  o.x = bfc(v.x); o.y = bfc(v.y); o.z = bfc(v.z); o.w = bfc(v.w);
  ((ushort4*)y)[i] = o;
}

// ---------------- merged: 4 weight transposes (fp32->bf16) + bias concat ----------------
__global__ __launch_bounds__(256) void transpose_all(const float* __restrict__ Wq,
                                                     const float* __restrict__ Wk,
                                                     const float* __restrict__ Wv,
                                                     const float* __restrict__ Wo,
                                                     const float* __restrict__ bq,
                                                     const float* __restrict__ bk,
                                                     const float* __restrict__ bv,
                                                     u16* __restrict__ wqkvT,
                                                     u16* __restrict__ woT,
                                                     float* __restrict__ bqkv) {
  const int bid = blockIdx.x;
  if (bid >= 10240) {
    int i = (bid - 10240) * 256 + threadIdx.x;
    if (i < HDIM) bqkv[i] = bq[i];
    else if (i < HDIM + GD) bqkv[i] = bk[i - HDIM];
    else if (i < NQKV) bqkv[i] = bv[i - HDIM - GD];
    return;
  }
  const float* W; u16* Wt; int Cc, idx;
  if (bid < 4096)      { W = Wq; Wt = wqkvT;                              Cc = HDIM; idx = bid; }
  else if (bid < 5120) { W = Wk; Wt = wqkvT + (size_t)HDIM * HDIM;        Cc = GD;   idx = bid - 4096; }
  else if (bid < 6144) { W = Wv; Wt = wqkvT + (size_t)(HDIM + GD) * HDIM; Cc = GD;   idx = bid - 5120; }
  else                 { W = Wo; Wt = woT;                                Cc = HDIM; idx = bid - 6144; }
  const int gx = Cc / 32;
  const int bx = (idx % gx) * 32, by = (idx / gx) * 32;

  __shared__ float t[32][33];
  int tx = threadIdx.x & 31, ty = threadIdx.x >> 5;
#pragma unroll
  for (int i = 0; i < 4; ++i)
    t[ty + i * 8][tx] = W[(size_t)(by + ty + i * 8) * Cc + bx + tx];
  __syncthreads();
#pragma unroll
  for (int i = 0; i < 4; ++i)
    Wt[(size_t)(bx + ty + i * 8) * HDIM + by + tx] = bfc(t[tx][ty + i * 8]);
}

// ---------------- v slice of qkv [MROWS,NQKV] -> vT [B,GD,S] bf16 ----------------
__global__ __launch_bounds__(256) void transpose_v_kernel(const u16* __restrict__ QKV,
                                                          u16* __restrict__ Vt) {
  __shared__ u16 t[32][33];
  int b = blockIdx.z;
  const u16* Vb = QKV + (size_t)b * S_LEN * NQKV + HDIM + GD;
  u16* Vtb = Vt + (size_t)b * GD * S_LEN;
  int bx = blockIdx.x * 32;
  int by = blockIdx.y * 32;
  int tx = threadIdx.x & 31, ty = threadIdx.x >> 5;
#pragma unroll
  for (int i = 0; i < 4; ++i)
    t[ty + i * 8][tx] = Vb[(size_t)(by + ty + i * 8) * NQKV + bx + tx];
  __syncthreads();
#pragma unroll
  for (int i = 0; i < 4; ++i)
    Vtb[(size_t)(bx + ty + i * 8) * S_LEN + by + tx] = t[tx][ty + i * 8];
}

// ---------------- bf16 GEMM: C[M,N] = (A[M,K] @ Bt[N,K]^T + bias) * alpha(col) ----------------
// T1 bijective XCD swizzle (m204). alpha tile-uniform via qlim (128-aligned).
__global__ __launch_bounds__(256) void gemm_bf16(const u16* __restrict__ A,
                                                 const u16* __restrict__ Bt,
                                                 const float* __restrict__ bias,
                                                 void* __restrict__ C,
                                                 int M, int N, int K,
                                                 float alphaA, float alphaB, int qlim,
                                                 int obf) {
  __shared__ __attribute__((aligned(16))) u16 As[128 * 32];
  __shared__ __attribute__((aligned(16))) u16 Bs[128 * 32];
  const int tid = threadIdx.x, lane = tid & 63, wv = tid >> 6;
  const int wr = wv >> 1, wc = wv & 1;
  const int r16 = lane & 15, kg = lane >> 4;

  const int nwg = gridDim.x * gridDim.y;
  const int orig = blockIdx.y * gridDim.x + blockIdx.x;
  const int qq = nwg >> 3, rr = nwg & 7;
  const int xcd = orig & 7, loc = orig >> 3;
  const int swz = (xcd < rr ? xcd * (qq + 1) : rr * (qq + 1) + (xcd - rr) * qq) + loc;
  const int m0 = (swz / gridDim.x) * 128, n0 = (swz % gridDim.x) * 128;
  const float alpha = (n0 < qlim) ? alphaA : alphaB;

  f32x4 acc[4][4];
#pragma unroll
  for (int m = 0; m < 4; ++m)
#pragma unroll
    for (int n = 0; n < 4; ++n) acc[m][n] = (f32x4)0.0f;

  auto stage = [&](int k0) {
#pragma unroll
    for (int i = 0; i < 2; ++i) {
      int chunk = i * 256 + wv * 64 + lane;
      int row = chunk >> 2, cc = chunk & 3;
      glds16(A + (size_t)(m0 + row) * K + k0 + cc * 8, &As[(i * 256 + wv * 64) * 8]);
    }
#pragma unroll
    for (int i = 0; i < 2; ++i) {
      int chunk = i * 256 + wv * 64 + lane;
      int row = chunk >> 2, cc = chunk & 3;
      glds16(Bt + (size_t)(n0 + row) * K + k0 + cc * 8, &Bs[(i * 256 + wv * 64) * 8]);
    }
  };

  stage(0);
  const int nk = K / 32;
  for (int kt = 0; kt < nk; ++kt) {
    asm volatile("s_waitcnt vmcnt(0)" ::: "memory");
    __syncthreads();
    bf16x8 af[4], bfr[4];
#pragma unroll
    for (int m = 0; m < 4; ++m)
      af[m] = *(const bf16x8*)&As[(wr * 64 + m * 16 + r16) * 32 + kg * 8];
#pragma unroll
    for (int n = 0; n < 4; ++n)
      bfr[n] = *(const bf16x8*)&Bs[(wc * 64 + n * 16 + r16) * 32 + kg * 8];
    __syncthreads();
    if (kt + 1 < nk) stage((kt + 1) * 32);
#pragma unroll
    for (int m = 0; m < 4; ++m)
#pragma unroll
      for (int n = 0; n < 4; ++n)
        acc[m][n] = __builtin_amdgcn_mfma_f32_16x16x32_bf16(af[m], bfr[n], acc[m][n], 0, 0, 0);
  }

#pragma unroll
  for (int m = 0; m < 4; ++m) {
    int row = m0 + wr * 64 + m * 16 + kg * 4;
#pragma unroll
    for (int n = 0; n < 4; ++n) {
      int col = n0 + wc * 64 + n * 16 + r16;
      float bb = bias ? bias[col] : 0.0f;
#pragma unroll
      for (int i = 0; i < 4; ++i) {
        float val = (acc[m][n][i] + bb) * alpha;
        if (obf) ((u16*)C)[(size_t)(row + i) * N + col] = bfc(val);
        else     ((float*)C)[(size_t)(row + i) * N + col] = val;
      }
    }
  }
}

// ---------------- fused GQA flash attention (R12: 32x32 swapped-QK^T, dbuf counted-vmcnt) ----------------
// Best measured attn (119.5us, VGPR 64, 4 blocks/CU). 4 waves x 32 queries.
// stage(t+1) -> vmcnt(4) -> barrier_B -> compute(cur) -> barrier_A; loads stay
// in flight across both barriers. Shift-free softmax; l on the matrix pipe.
__global__ __launch_bounds__(256, 4) void gqa_attn_kernel(const u16* __restrict__ qkv,
                                                          const u16* __restrict__ vT,
                                                          u16* __restrict__ att) {
  __shared__ __attribute__((aligned(16))) u16 Ks[2][64 * 64];   // [key][d]
  __shared__ __attribute__((aligned(16))) u16 Vs[2][64 * 64];   // [d][key]

  const int bid = blockIdx.x;
  const int qt = bid & 15;
  const int h = (bid >> 4) & 31;
  const int b = bid >> 9;
  const int g = h >> 2;                 // R = 4
  const int tid = threadIdx.x, lane = tid & 63, wv = tid >> 6;
  const int q31 = lane & 31, hi = lane >> 5;
  const int qbase = qt * 128 + wv * 32;

  const u16* qrow = qkv + (size_t)(b * S_LEN + qbase + q31) * NQKV + h * 64;
  bf16x8 qf[4];
#pragma unroll
  for (int d = 0; d < 4; ++d)
    qf[d] = *(const bf16x8*)(qrow + d * 16 + hi * 8);

  union { u16 w[8]; bf16x8 v; } uo;
#pragma unroll
  for (int i = 0; i < 8; ++i) uo.w[i] = 0x3F80;
  const bf16x8 onesf = uo.v;

  const u16* kbase = qkv + (size_t)(b * S_LEN) * NQKV + HDIM + g * 64;
  const u16* vbase = vT + (size_t)((b * NKV + g) * 64) * S_LEN;

  auto stageK = [&](int t, int buf) {
    const int kk0 = t * 64;
#pragma unroll
    for (int i = 0; i < 2; ++i) {
      int chunk = i * 256 + wv * 64 + lane;
      int row = chunk >> 3, cc = chunk & 7;
      int cs = cc ^ (row & 7);          // inverse-swizzled global source chunk
      glds16(kbase + (size_t)(kk0 + row) * NQKV + cs * 8, &Ks[buf][(i * 256 + wv * 64) * 8]);
      glds16(vbase + (size_t)row * S_LEN + kk0 + cs * 8, &Vs[buf][(i * 256 + wv * 64) * 8]);
    }
  };

  f32x16 o0 = (f32x16)0.0f, o1 = (f32x16)0.0f, ol = (f32x16)0.0f;

  stageK(0, 0);
  const int sw = q31 & 7;               // read-side swizzle (row&7)
  const int NT = S_LEN / 64;            // 32 tiles
  for (int t = 0; t < NT; ++t) {
    const int cur = t & 1;
    if (t + 1 < NT) {
      stageK(t + 1, cur ^ 1);
      asm volatile("s_waitcnt vmcnt(4)" ::: "memory");
    } else {
      asm volatile("s_waitcnt vmcnt(0)" ::: "memory");
    }
    __builtin_amdgcn_s_barrier();
    asm volatile("" ::: "memory");

    f32x16 p0 = (f32x16)0.0f, p1 = (f32x16)0.0f;
    __builtin_amdgcn_s_setprio(1);
#pragma unroll
    for (int d = 0; d < 4; ++d) {
      int ch = ((d * 2 + hi) ^ sw) * 8;
      bf16x8 kf0 = *(const bf16x8*)&Ks[cur][q31 * 64 + ch];
      bf16x8 kf1 = *(const bf16x8*)&Ks[cur][(32 + q31) * 64 + ch];
      p0 = __builtin_amdgcn_mfma_f32_32x32x16_bf16(kf0, qf[d], p0, 0, 0, 0);
      p1 = __builtin_amdgcn_mfma_f32_32x32x16_bf16(kf1, qf[d], p1, 0, 0, 0);
    }
    __builtin_amdgcn_s_setprio(0);

#pragma unroll
    for (int r = 0; r < 16; ++r) {
      p0[r] = exp2f(p0[r]);
      p1[r] = exp2f(p1[r]);
    }

    bf16x8 pa[4];
#pragma unroll
    for (int kk = 0; kk < 2; ++kk) {
      int w0 = cvtpk(p0[kk * 8 + 0], p0[kk * 8 + 1]);
      int w1 = cvtpk(p0[kk * 8 + 2], p0[kk * 8 + 3]);
      int w2 = cvtpk(p0[kk * 8 + 4], p0[kk * 8 + 5]);
      int w3 = cvtpk(p0[kk * 8 + 6], p0[kk * 8 + 7]);
      auto s0 = __builtin_amdgcn_permlane32_swap(w0, w2, false, false);
      auto s1 = __builtin_amdgcn_permlane32_swap(w1, w3, false, false);
      union { int w[4]; bf16x8 v; } u;
      u.w[0] = s0[0]; u.w[1] = s1[0]; u.w[2] = s0[1]; u.w[3] = s1[1];
      pa[kk] = u.v;
    }
#pragma unroll
    for (int kk = 0; kk < 2; ++kk) {
      int w0 = cvtpk(p1[kk * 8 + 0], p1[kk * 8 + 1]);
      int w1 = cvtpk(p1[kk * 8 + 2], p1[kk * 8 + 3]);
      int w2 = cvtpk(p1[kk * 8 + 4], p1[kk * 8 + 5]);
      int w3 = cvtpk(p1[kk * 8 + 6], p1[kk * 8 + 7]);
      auto s0 = __builtin_amdgcn_permlane32_swap(w0, w2, false, false);
      auto s1 = __builtin_amdgcn_permlane32_swap(w1, w3, false, false);
      union { int w[4]; bf16x8 v; } u;
      u.w[0] = s0[0]; u.w[1] = s1[0]; u.w[2] = s0[1]; u.w[3] = s1[1];
      pa[2 + kk] = u.v;
    }

    __builtin_amdgcn_s_setprio(1);
#pragma unroll
    for (int ks = 0; ks < 4; ++ks) {
      int ch = (((ks * 2 + hi)) ^ sw) * 8;
      bf16x8 vf0 = *(const bf16x8*)&Vs[cur][q31 * 64 + ch];
      bf16x8 vf1 = *(const bf16x8*)&Vs[cur][(32 + q31) * 64 + ch];
      o0 = __builtin_amdgcn_mfma_f32_32x32x16_bf16(pa[ks], vf0, o0, 0, 0, 0);
      o1 = __builtin_amdgcn_mfma_f32_32x32x16_bf16(pa[ks], vf1, o1, 0, 0, 0);
      ol = __builtin_amdgcn_mfma_f32_32x32x16_bf16(pa[ks], onesf, ol, 0, 0, 0);
    }
    __builtin_amdgcn_s_setprio(0);
    asm volatile("" ::: "memory");
    __builtin_amdgcn_s_barrier();
    asm volatile("" ::: "memory");
  }

  u16* obase = att + (size_t)(b * S_LEN + qbase) * HDIM + h * 64 + q31;
#pragma unroll
  for (int r = 0; r < 16; ++r) {
    int qq2 = (r & 3) + 8 * (r >> 2) + 4 * hi;
    float inv = 1.0f / ol[r];
    obase[(size_t)qq2 * HDIM]      = bfc(o0[r] * inv);
    obase[(size_t)qq2 * HDIM + 32] = bfc(o1[r] * inv);
  }
}

extern "C" void kernel_launch(void* const* d_in, const int* in_sizes, int n_in,
                              void* d_out, int out_size, void* d_ws, size_t ws_size,
                              hipStream_t stream) {
  const float* x  = (const float*)d_in[0];
  const float* Wq = (const float*)d_in[1];
  const float* bq = (const float*)d_in[2];
  const float* Wk = (const float*)d_in[3];
  const float* bk = (const float*)d_in[4];
  const float* Wv = (const float*)d_in[5];
  const float* bv = (const float*)d_in[6];
  const float* Wo = (const float*)d_in[7];
  const float* bo = (const float*)d_in[8];
  float* out = (float*)d_out;

  char* p = (char*)d_ws;
  u16* xb    = (u16*)p; p += (size_t)MROWS * HDIM * 2;
  u16* wqkvT = (u16*)p; p += (size_t)NQKV * HDIM * 2;     // [3072 x 2048] bf16
  u16* woT   = (u16*)p; p += (size_t)HDIM * HDIM * 2;
  float* bqkv = (float*)p; p += (size_t)NQKV * 4;
  u16* qkv   = (u16*)p; p += (size_t)MROWS * NQKV * 2;    // [4096 x 3072] bf16
  u16* vtb   = (u16*)p; p += (size_t)MROWS * GD * 2;
  u16* attb  = (u16*)p; p += (size_t)MROWS * HDIM * 2;

  const float aQ = 0.18033688011112042f;  // (1/sqrt(64)) * log2(e)

  // convert x to bf16
  cvt_f32_bf16_kernel<<<(MROWS * HDIM / 4 + 255) / 256, 256, 0, stream>>>(x, xb, MROWS * HDIM / 4);
  // merged weight transposes + bias concat (one launch)
  transpose_all<<<10252, 256, 0, stream>>>(Wq, Wk, Wv, Wo, bq, bk, bv, wqkvT, woT, bqkv);
  // fused QKV projection: Q cols scaled by aQ (exp2-domain softmax)
  gemm_bf16<<<dim3(NQKV / 128, MROWS / 128), 256, 0, stream>>>(xb, wqkvT, bqkv, qkv,
                                                               MROWS, NQKV, HDIM, aQ, 1.0f, HDIM, 1);
  // V -> V^T per batch
  transpose_v_kernel<<<dim3(GD / 32, S_LEN / 32, BATCH), 256, 0, stream>>>(qkv, vtb);
  // fused attention: R12 dbuf counted-vmcnt (best measured: 119.5us)
  gqa_attn_kernel<<<BATCH * 32 * 16, 256, 0, stream>>>(qkv, vtb, attb);
  // output projection -> fp32 out
  gemm_bf16<<<dim3(HDIM / 128, MROWS / 128), 256, 0, stream>>>(attb, woT, bo, out,
                                                               MROWS, HDIM, HDIM, 1.0f, 1.0f, HDIM, 0);
}

// Round 16
// 222.943 us; speedup vs baseline: 1.1100x; 1.0610x over previous
//
#include <hip/hip_runtime.h>
#include <stdint.h>

#define S_LEN 2048
#define HDIM  2048
#define BATCH 2
#define NKV   8
#define GD    512      // NKV * 64
#define MROWS 4096     // BATCH * S_LEN
#define NQKV  3072     // HDIM + 2*GD

typedef __attribute__((ext_vector_type(8))) __bf16 bf16x8;
typedef __attribute__((ext_vector_type(4))) float f32x4;
typedef __attribute__((ext_vector_type(16))) float f32x16;
typedef unsigned short u16;

// native f32->bf16 (RNE)
__device__ __forceinline__ u16 bfc(float f) {
  union { __bf16 b; u16 u; } v; v.b = (__bf16)f; return v.u;
}
// packed pair convert: one v_cvt_pk_bf16_f32 (T12)
__device__ __forceinline__ int cvtpk(float lo, float hi) {
  int r; asm("v_cvt_pk_bf16_f32 %0, %1, %2" : "=v"(r) : "v"(lo), "v"(hi)); return r;
}

__device__ __forceinline__ void glds16(const void* g, void* lds) {
  __builtin_amdgcn_global_load_lds((const __attribute__((address_space(1))) void*)g,
                                   (__attribute__((address_space(3))) void*)lds, 16, 0, 0);
}

// ---------------- fp32 -> bf16 elementwise convert (vectorized) ----------------
__global__ __launch_bounds__(256) void cvt_f32_bf16_kernel(const float* __restrict__ x,
                                                           u16* __restrict__ y, int n4) {
  int i = blockIdx.x * 256 + threadIdx.x;
  if (i >= n4) return;
  const float4 v = ((const float4*)x)[i];
  ushort4 o;
  o.x = bfc(v.x); o.y = bfc(v.y); o.z = bfc(v.z); o.w = bfc(v.w);
  ((ushort4*)y)[i] = o;
}

// ---------------- merged: 4 weight transposes (fp32->bf16) + bias concat ----------------
__global__ __launch_bounds__(256) void transpose_all(const float* __restrict__ Wq,
                                                     const float* __restrict__ Wk,
                                                     const float* __restrict__ Wv,
                                                     const float* __restrict__ Wo,
                                                     const float* __restrict__ bq,
                                                     const float* __restrict__ bk,
                                                     const float* __restrict__ bv,
                                                     u16* __restrict__ wqkvT,
                                                     u16* __restrict__ woT,
                                                     float* __restrict__ bqkv) {
  const int bid = blockIdx.x;
  if (bid >= 10240) {
    int i = (bid - 10240) * 256 + threadIdx.x;
    if (i < HDIM) bqkv[i] = bq[i];
    else if (i < HDIM + GD) bqkv[i] = bk[i - HDIM];
    else if (i < NQKV) bqkv[i] = bv[i - HDIM - GD];
    return;
  }
  const float* W; u16* Wt; int Cc, idx;
  if (bid < 4096)      { W = Wq; Wt = wqkvT;                              Cc = HDIM; idx = bid; }
  else if (bid < 5120) { W = Wk; Wt = wqkvT + (size_t)HDIM * HDIM;        Cc = GD;   idx = bid - 4096; }
  else if (bid < 6144) { W = Wv; Wt = wqkvT + (size_t)(HDIM + GD) * HDIM; Cc = GD;   idx = bid - 5120; }
  else                 { W = Wo; Wt = woT;                                Cc = HDIM; idx = bid - 6144; }
  const int gx = Cc / 32;
  const int bx = (idx % gx) * 32, by = (idx / gx) * 32;

  __shared__ float t[32][33];
  int tx = threadIdx.x & 31, ty = threadIdx.x >> 5;
#pragma unroll
  for (int i = 0; i < 4; ++i)
    t[ty + i * 8][tx] = W[(size_t)(by + ty + i * 8) * Cc + bx + tx];
  __syncthreads();
#pragma unroll
  for (int i = 0; i < 4; ++i)
    Wt[(size_t)(bx + ty + i * 8) * HDIM + by + tx] = bfc(t[tx][ty + i * 8]);
}

// ---------------- v slice of qkv [MROWS,NQKV] -> vT [B,GD,S] bf16 ----------------
__global__ __launch_bounds__(256) void transpose_v_kernel(const u16* __restrict__ QKV,
                                                          u16* __restrict__ Vt) {
  __shared__ u16 t[32][33];
  int b = blockIdx.z;
  const u16* Vb = QKV + (size_t)b * S_LEN * NQKV + HDIM + GD;
  u16* Vtb = Vt + (size_t)b * GD * S_LEN;
  int bx = blockIdx.x * 32;
  int by = blockIdx.y * 32;
  int tx = threadIdx.x & 31, ty = threadIdx.x >> 5;
#pragma unroll
  for (int i = 0; i < 4; ++i)
    t[ty + i * 8][tx] = Vb[(size_t)(by + ty + i * 8) * NQKV + bx + tx];
  __syncthreads();
#pragma unroll
  for (int i = 0; i < 4; ++i)
    Vtb[(size_t)(bx + ty + i * 8) * S_LEN + by + tx] = t[tx][ty + i * 8];
}

// ---------------- bf16 GEMM, BK=64: C[M,N] = (A[M,K] @ Bt[N,K]^T + bias) * alpha(col) ----------------
// vs BK=32: half the vmcnt(0)+barrier drains (the m97 structure's ~20% stall).
// [128][64] u16 rows are 128B => 16-way bank conflict unswizzled; fixed with the
// attention kernel's proven XOR pair: source chunk cc^=(row&7), read chunk ^=(r16&7).
// T1 bijective XCD swizzle (m204). alpha tile-uniform via qlim (128-aligned).
__global__ __launch_bounds__(256) void gemm_bf16(const u16* __restrict__ A,
                                                 const u16* __restrict__ Bt,
                                                 const float* __restrict__ bias,
                                                 void* __restrict__ C,
                                                 int M, int N, int K,
                                                 float alphaA, float alphaB, int qlim,
                                                 int obf) {
  __shared__ __attribute__((aligned(16))) u16 As[128 * 64];
  __shared__ __attribute__((aligned(16))) u16 Bs[128 * 64];
  const int tid = threadIdx.x, lane = tid & 63, wv = tid >> 6;
  const int wr = wv >> 1, wc = wv & 1;
  const int r16 = lane & 15, kg = lane >> 4;

  const int nwg = gridDim.x * gridDim.y;
  const int orig = blockIdx.y * gridDim.x + blockIdx.x;
  const int qq = nwg >> 3, rr = nwg & 7;
  const int xcd = orig & 7, loc = orig >> 3;
  const int swz = (xcd < rr ? xcd * (qq + 1) : rr * (qq + 1) + (xcd - rr) * qq) + loc;
  const int m0 = (swz / gridDim.x) * 128, n0 = (swz % gridDim.x) * 128;
  const float alpha = (n0 < qlim) ? alphaA : alphaB;

  f32x4 acc[4][4];
#pragma unroll
  for (int m = 0; m < 4; ++m)
#pragma unroll
    for (int n = 0; n < 4; ++n) acc[m][n] = (f32x4)0.0f;

  // 1024 16B-chunks per matrix; 4 glds16/thread each. Source pre-swizzled
  // (cs = cc ^ (row&7)), LDS dest linear (both-sides-or-neither, rule #21).
  auto stage = [&](int k0) {
#pragma unroll
    for (int i = 0; i < 4; ++i) {
      int chunk = i * 256 + wv * 64 + lane;
      int row = chunk >> 3, cc = chunk & 7;
      int cs = cc ^ (row & 7);
      glds16(A + (size_t)(m0 + row) * K + k0 + cs * 8, &As[(i * 256 + wv * 64) * 8]);
    }
#pragma unroll
    for (int i = 0; i < 4; ++i) {
      int chunk = i * 256 + wv * 64 + lane;
      int row = chunk >> 3, cc = chunk & 7;
      int cs = cc ^ (row & 7);
      glds16(Bt + (size_t)(n0 + row) * K + k0 + cs * 8, &Bs[(i * 256 + wv * 64) * 8]);
    }
  };

  stage(0);
  const int nk = K / 64;
  const int rsw = r16 & 7;              // read-side swizzle (row&7 == r16&7)
  for (int kt = 0; kt < nk; ++kt) {
    asm volatile("s_waitcnt vmcnt(0)" ::: "memory");
    __syncthreads();
    bf16x8 af[4][2], bfr[4][2];
#pragma unroll
    for (int m = 0; m < 4; ++m)
#pragma unroll
      for (int ks = 0; ks < 2; ++ks)
        af[m][ks] = *(const bf16x8*)&As[(wr * 64 + m * 16 + r16) * 64 + (((ks * 4 + kg) ^ rsw) * 8)];
#pragma unroll
    for (int n = 0; n < 4; ++n)
#pragma unroll
      for (int ks = 0; ks < 2; ++ks)
        bfr[n][ks] = *(const bf16x8*)&Bs[(wc * 64 + n * 16 + r16) * 64 + (((ks * 4 + kg) ^ rsw) * 8)];
    __syncthreads();
    if (kt + 1 < nk) stage((kt + 1) * 64);
#pragma unroll
    for (int ks = 0; ks < 2; ++ks)
#pragma unroll
      for (int m = 0; m < 4; ++m)
#pragma unroll
        for (int n = 0; n < 4; ++n)
          acc[m][n] = __builtin_amdgcn_mfma_f32_16x16x32_bf16(af[m][ks], bfr[n][ks], acc[m][n], 0, 0, 0);
  }

#pragma unroll
  for (int m = 0; m < 4; ++m) {
    int row = m0 + wr * 64 + m * 16 + kg * 4;
#pragma unroll
    for (int n = 0; n < 4; ++n) {
      int col = n0 + wc * 64 + n * 16 + r16;
      float bb = bias ? bias[col] : 0.0f;
#pragma unroll
      for (int i = 0; i < 4; ++i) {
        float val = (acc[m][n][i] + bb) * alpha;
        if (obf) ((u16*)C)[(size_t)(row + i) * N + col] = bfc(val);
        else     ((float*)C)[(size_t)(row + i) * N + col] = val;
      }
    }
  }
}

// ---------------- fused GQA flash attention (R12: 32x32 swapped-QK^T, dbuf counted-vmcnt) ----------------
// Best measured attn (119.5us, VGPR 64, 4 blocks/CU). 4 waves x 32 queries.
__global__ __launch_bounds__(256, 4) void gqa_attn_kernel(const u16* __restrict__ qkv,
                                                          const u16* __restrict__ vT,
                                                          u16* __restrict__ att) {
  __shared__ __attribute__((aligned(16))) u16 Ks[2][64 * 64];   // [key][d]
  __shared__ __attribute__((aligned(16))) u16 Vs[2][64 * 64];   // [d][key]

  const int bid = blockIdx.x;
  const int qt = bid & 15;
  const int h = (bid >> 4) & 31;
  const int b = bid >> 9;
  const int g = h >> 2;                 // R = 4
  const int tid = threadIdx.x, lane = tid & 63, wv = tid >> 6;
  const int q31 = lane & 31, hi = lane >> 5;
  const int qbase = qt * 128 + wv * 32;

  const u16* qrow = qkv + (size_t)(b * S_LEN + qbase + q31) * NQKV + h * 64;
  bf16x8 qf[4];
#pragma unroll
  for (int d = 0; d < 4; ++d)
    qf[d] = *(const bf16x8*)(qrow + d * 16 + hi * 8);

  union { u16 w[8]; bf16x8 v; } uo;
#pragma unroll
  for (int i = 0; i < 8; ++i) uo.w[i] = 0x3F80;
  const bf16x8 onesf = uo.v;

  const u16* kbase = qkv + (size_t)(b * S_LEN) * NQKV + HDIM + g * 64;
  const u16* vbase = vT + (size_t)((b * NKV + g) * 64) * S_LEN;

  auto stageK = [&](int t, int buf) {
    const int kk0 = t * 64;
#pragma unroll
    for (int i = 0; i < 2; ++i) {
      int chunk = i * 256 + wv * 64 + lane;
      int row = chunk >> 3, cc = chunk & 7;
      int cs = cc ^ (row & 7);          // inverse-swizzled global source chunk
      glds16(kbase + (size_t)(kk0 + row) * NQKV + cs * 8, &Ks[buf][(i * 256 + wv * 64) * 8]);
      glds16(vbase + (size_t)row * S_LEN + kk0 + cs * 8, &Vs[buf][(i * 256 + wv * 64) * 8]);
    }
  };

  f32x16 o0 = (f32x16)0.0f, o1 = (f32x16)0.0f, ol = (f32x16)0.0f;

  stageK(0, 0);
  const int sw = q31 & 7;               // read-side swizzle (row&7)
  const int NT = S_LEN / 64;            // 32 tiles
  for (int t = 0; t < NT; ++t) {
    const int cur = t & 1;
    if (t + 1 < NT) {
      stageK(t + 1, cur ^ 1);
      asm volatile("s_waitcnt vmcnt(4)" ::: "memory");
    } else {
      asm volatile("s_waitcnt vmcnt(0)" ::: "memory");
    }
    __builtin_amdgcn_s_barrier();
    asm volatile("" ::: "memory");

    f32x16 p0 = (f32x16)0.0f, p1 = (f32x16)0.0f;
    __builtin_amdgcn_s_setprio(1);
#pragma unroll
    for (int d = 0; d < 4; ++d) {
      int ch = ((d * 2 + hi) ^ sw) * 8;
      bf16x8 kf0 = *(const bf16x8*)&Ks[cur][q31 * 64 + ch];
      bf16x8 kf1 = *(const bf16x8*)&Ks[cur][(32 + q31) * 64 + ch];
      p0 = __builtin_amdgcn_mfma_f32_32x32x16_bf16(kf0, qf[d], p0, 0, 0, 0);
      p1 = __builtin_amdgcn_mfma_f32_32x32x16_bf16(kf1, qf[d], p1, 0, 0, 0);
    }
    __builtin_amdgcn_s_setprio(0);

#pragma unroll
    for (int r = 0; r < 16; ++r) {
      p0[r] = exp2f(p0[r]);
      p1[r] = exp2f(p1[r]);
    }

    bf16x8 pa[4];
#pragma unroll
    for (int kk = 0; kk < 2; ++kk) {
      int w0 = cvtpk(p0[kk * 8 + 0], p0[kk * 8 + 1]);
      int w1 = cvtpk(p0[kk * 8 + 2], p0[kk * 8 + 3]);
      int w2 = cvtpk(p0[kk * 8 + 4], p0[kk * 8 + 5]);
      int w3 = cvtpk(p0[kk * 8 + 6], p0[kk * 8 + 7]);
      auto s0 = __builtin_amdgcn_permlane32_swap(w0, w2, false, false);
      auto s1 = __builtin_amdgcn_permlane32_swap(w1, w3, false, false);
      union { int w[4]; bf16x8 v; } u;
      u.w[0] = s0[0]; u.w[1] = s1[0]; u.w[2] = s0[1]; u.w[3] = s1[1];
      pa[kk] = u.v;
    }
#pragma unroll
    for (int kk = 0; kk < 2; ++kk) {
      int w0 = cvtpk(p1[kk * 8 + 0], p1[kk * 8 + 1]);
      int w1 = cvtpk(p1[kk * 8 + 2], p1[kk * 8 + 3]);
      int w2 = cvtpk(p1[kk * 8 + 4], p1[kk * 8 + 5]);
      int w3 = cvtpk(p1[kk * 8 + 6], p1[kk * 8 + 7]);
      auto s0 = __builtin_amdgcn_permlane32_swap(w0, w2, false, false);
      auto s1 = __builtin_amdgcn_permlane32_swap(w1, w3, false, false);
      union { int w[4]; bf16x8 v; } u;
      u.w[0] = s0[0]; u.w[1] = s1[0]; u.w[2] = s0[1]; u.w[3] = s1[1];
      pa[2 + kk] = u.v;
    }

    __builtin_amdgcn_s_setprio(1);
#pragma unroll
    for (int ks = 0; ks < 4; ++ks) {
      int ch = (((ks * 2 + hi)) ^ sw) * 8;
      bf16x8 vf0 = *(const bf16x8*)&Vs[cur][q31 * 64 + ch];
      bf16x8 vf1 = *(const bf16x8*)&Vs[cur][(32 + q31) * 64 + ch];
      o0 = __builtin_amdgcn_mfma_f32_32x32x16_bf16(pa[ks], vf0, o0, 0, 0, 0);
      o1 = __builtin_amdgcn_mfma_f32_32x32x16_bf16(pa[ks], vf1, o1, 0, 0, 0);
      ol = __builtin_amdgcn_mfma_f32_32x32x16_bf16(pa[ks], onesf, ol, 0, 0, 0);
    }
    __builtin_amdgcn_s_setprio(0);
    asm volatile("" ::: "memory");
    __builtin_amdgcn_s_barrier();
    asm volatile("" ::: "memory");
  }

  u16* obase = att + (size_t)(b * S_LEN + qbase) * HDIM + h * 64 + q31;
#pragma unroll
  for (int r = 0; r < 16; ++r) {
    int qq2 = (r & 3) + 8 * (r >> 2) + 4 * hi;
    float inv = 1.0f / ol[r];
    obase[(size_t)qq2 * HDIM]      = bfc(o0[r] * inv);
    obase[(size_t)qq2 * HDIM + 32] = bfc(o1[r] * inv);
  }
}

extern "C" void kernel_launch(void* const* d_in, const int* in_sizes, int n_in,
                              void* d_out, int out_size, void* d_ws, size_t ws_size,
                              hipStream_t stream) {
  const float* x  = (const float*)d_in[0];
  const float* Wq = (const float*)d_in[1];
  const float* bq = (const float*)d_in[2];
  const float* Wk = (const float*)d_in[3];
  const float* bk = (const float*)d_in[4];
  const float* Wv = (const float*)d_in[5];
  const float* bv = (const float*)d_in[6];
  const float* Wo = (const float*)d_in[7];
  const float* bo = (const float*)d_in[8];
  float* out = (float*)d_out;

  char* p = (char*)d_ws;
  u16* xb    = (u16*)p; p += (size_t)MROWS * HDIM * 2;
  u16* wqkvT = (u16*)p; p += (size_t)NQKV * HDIM * 2;     // [3072 x 2048] bf16
  u16* woT   = (u16*)p; p += (size_t)HDIM * HDIM * 2;
  float* bqkv = (float*)p; p += (size_t)NQKV * 4;
  u16* qkv   = (u16*)p; p += (size_t)MROWS * NQKV * 2;    // [4096 x 3072] bf16
  u16* vtb   = (u16*)p; p += (size_t)MROWS * GD * 2;
  u16* attb  = (u16*)p; p += (size_t)MROWS * HDIM * 2;

  const float aQ = 0.18033688011112042f;  // (1/sqrt(64)) * log2(e)

  // convert x to bf16
  cvt_f32_bf16_kernel<<<(MROWS * HDIM / 4 + 255) / 256, 256, 0, stream>>>(x, xb, MROWS * HDIM / 4);
  // merged weight transposes + bias concat (one launch)
  transpose_all<<<10252, 256, 0, stream>>>(Wq, Wk, Wv, Wo, bq, bk, bv, wqkvT, woT, bqkv);
  // fused QKV projection: Q cols scaled by aQ (exp2-domain softmax); BK=64
  gemm_bf16<<<dim3(NQKV / 128, MROWS / 128), 256, 0, stream>>>(xb, wqkvT, bqkv, qkv,
                                                               MROWS, NQKV, HDIM, aQ, 1.0f, HDIM, 1);
  // V -> V^T per batch
  transpose_v_kernel<<<dim3(GD / 32, S_LEN / 32, BATCH), 256, 0, stream>>>(qkv, vtb);
  // fused attention: R12 dbuf counted-vmcnt (best measured: 119.5us)
  gqa_attn_kernel<<<BATCH * 32 * 16, 256, 0, stream>>>(qkv, vtb, attb);
  // output projection -> fp32 out; BK=64
  gemm_bf16<<<dim3(HDIM / 128, MROWS / 128), 256, 0, stream>>>(attb, woT, bo, out,
                                                               MROWS, HDIM, HDIM, 1.0f, 1.0f, HDIM, 0);
}